// Round 1
// baseline (430.359 us; speedup 1.0000x reference)
//
#include <hip/hip_runtime.h>
#include <stdint.h>

typedef __attribute__((ext_vector_type(4))) float  floatx4;
typedef __attribute__((ext_vector_type(8))) short  short8;
typedef __attribute__((ext_vector_type(8))) __bf16 bf16x8;

__device__ __forceinline__ unsigned short f2bf(float f) {
  unsigned int u = __builtin_bit_cast(unsigned int, f);
  u += 0x7fffu + ((u >> 16) & 1u);   // round-to-nearest-even
  return (unsigned short)(u >> 16);
}

// ---------------- cast x (fp32 -> bf16), 8 elems/thread ----------------
__global__ __launch_bounds__(256) void cast_x_kernel(const float* __restrict__ X,
                                                     unsigned short* __restrict__ Xb) {
  size_t i = ((size_t)blockIdx.x * 256 + threadIdx.x) * 8;
  const floatx4* p = (const floatx4*)(X + i);
  floatx4 a = p[0], b = p[1];
  union { unsigned short us[8]; short8 v; } o;
  o.us[0] = f2bf(a[0]); o.us[1] = f2bf(a[1]); o.us[2] = f2bf(a[2]); o.us[3] = f2bf(a[3]);
  o.us[4] = f2bf(b[0]); o.us[5] = f2bf(b[1]); o.us[6] = f2bf(b[2]); o.us[7] = f2bf(b[3]);
  *(short8*)(Xb + i) = o.v;
}

// ------------- transpose+cast V [rows,cols] -> Vt [cols,rows] bf16 -------------
__global__ __launch_bounds__(256) void transpose_v_kernel(const float* __restrict__ V,
                                                          unsigned short* __restrict__ Vt,
                                                          int rows, int cols) {
  __shared__ float tile[32][33];  // +1 pad breaks bank conflicts
  int bx = blockIdx.x * 32;  // col block (rank dim)
  int by = blockIdx.y * 32;  // row block (out_h dim)
  int tx = threadIdx.x & 31;
  int ty = threadIdx.x >> 5; // 0..7
  for (int i = ty; i < 32; i += 8)
    tile[i][tx] = V[(size_t)(by + i) * cols + bx + tx];
  __syncthreads();
  for (int i = ty; i < 32; i += 8)
    Vt[(size_t)(bx + i) * rows + by + tx] = f2bf(tile[tx][i]);
}

// ------------- U' = bf16(U * S broadcast), 4 elems/thread -------------
__global__ __launch_bounds__(256) void prep_u_kernel(const float* __restrict__ U,
                                                     const float* __restrict__ S,
                                                     unsigned short* __restrict__ Ub,
                                                     unsigned int rankMask) {
  size_t i = ((size_t)blockIdx.x * 256 + threadIdx.x) * 4;
  floatx4 u = *(const floatx4*)(U + i);
  floatx4 s = *(const floatx4*)(S + (i & (size_t)rankMask));
  union { unsigned short us[4]; unsigned long long v; } o;
  o.us[0] = f2bf(u[0] * s[0]); o.us[1] = f2bf(u[1] * s[1]);
  o.us[2] = f2bf(u[2] * s[2]); o.us[3] = f2bf(u[3] * s[3]);
  *(unsigned long long*)(Ub + i) = o.v;
}

// ---------------- m97-style gemm_bt: C[M,N] = A[M,K] * Bt[N,K]^T ----------------
// 128x128 tile, BK=32, 256 threads = 4 waves in 2x2, each wave 4x4 MFMA tiles.
template <bool STORE_BF16>
__global__ __launch_bounds__(256, 2)
void gemm_bt_kernel(const unsigned short* __restrict__ A,
                    const unsigned short* __restrict__ Bt,
                    void* __restrict__ Cv,
                    const float* __restrict__ bias,
                    int M, int N, int K) {
  __shared__ unsigned short sA[128 * 32];
  __shared__ unsigned short sB[128 * 32];

  const int tid  = threadIdx.x;
  const int lane = tid & 63;
  const int wave = tid >> 6;
  const int wm = (wave >> 1) * 64;   // wave row offset in tile
  const int wn = (wave & 1) * 64;    // wave col offset in tile
  const int row0 = blockIdx.y * 128;
  const int col0 = blockIdx.x * 128;

  floatx4 acc[4][4];
  for (int i = 0; i < 4; ++i)
    for (int j = 0; j < 4; ++j)
      acc[i][j] = (floatx4){0.f, 0.f, 0.f, 0.f};

  const unsigned short* Ablk = A + (size_t)row0 * K;
  const unsigned short* Bblk = Bt + (size_t)col0 * K;

  // staging: 512 slots of 16B per tile (128 rows x 64B); slot = j*256 + tid
  const int r0 = tid >> 2,         c0 = (tid & 3) * 8;          // j=0
  const int r1 = (256 + tid) >> 2, c1 = (tid & 3) * 8;          // j=1 (tid&3 same)
  const int base0 = (wave * 64) * 8;         // ushort index, wave-uniform LDS base, j=0
  const int base1 = (256 + wave * 64) * 8;   // j=1

  const int mrow = lane & 15;
  const int quad = lane >> 4;

  typedef const __attribute__((address_space(1))) void* gptr_t;
  typedef __attribute__((address_space(3))) void*       lptr_t;

  for (int k0 = 0; k0 < K; k0 += 32) {
    __builtin_amdgcn_global_load_lds((gptr_t)(Ablk + (size_t)r0 * K + k0 + c0),
                                     (lptr_t)(sA + base0), 16, 0, 0);
    __builtin_amdgcn_global_load_lds((gptr_t)(Ablk + (size_t)r1 * K + k0 + c1),
                                     (lptr_t)(sA + base1), 16, 0, 0);
    __builtin_amdgcn_global_load_lds((gptr_t)(Bblk + (size_t)r0 * K + k0 + c0),
                                     (lptr_t)(sB + base0), 16, 0, 0);
    __builtin_amdgcn_global_load_lds((gptr_t)(Bblk + (size_t)r1 * K + k0 + c1),
                                     (lptr_t)(sB + base1), 16, 0, 0);
    __syncthreads();   // drains vmcnt -> tiles resident

    bf16x8 af[4], bfr[4];
#pragma unroll
    for (int mi = 0; mi < 4; ++mi)
      af[mi] = __builtin_bit_cast(bf16x8,
                *(const short8*)(sA + (wm + mi * 16 + mrow) * 32 + quad * 8));
#pragma unroll
    for (int ni = 0; ni < 4; ++ni)
      bfr[ni] = __builtin_bit_cast(bf16x8,
                *(const short8*)(sB + (wn + ni * 16 + mrow) * 32 + quad * 8));
#pragma unroll
    for (int mi = 0; mi < 4; ++mi)
#pragma unroll
      for (int ni = 0; ni < 4; ++ni)
        acc[mi][ni] = __builtin_amdgcn_mfma_f32_16x16x32_bf16(af[mi], bfr[ni],
                                                              acc[mi][ni], 0, 0, 0);
    __syncthreads();   // all reads done before next stage overwrites
  }

  // epilogue: C/D layout col=lane&15, row=quad*4+reg (verified m89/m91)
  const int orow = row0 + wm + quad * 4;
  const int ocol = col0 + wn + mrow;
  if (STORE_BF16) {
    unsigned short* C = (unsigned short*)Cv;
#pragma unroll
    for (int mi = 0; mi < 4; ++mi)
#pragma unroll
      for (int r = 0; r < 4; ++r) {
        size_t rowoff = (size_t)(orow + mi * 16 + r) * N;
#pragma unroll
        for (int ni = 0; ni < 4; ++ni)
          C[rowoff + ocol + ni * 16] = f2bf(acc[mi][ni][r]);
      }
  } else {
    float* C = (float*)Cv;
    float bv[4];
#pragma unroll
    for (int ni = 0; ni < 4; ++ni) bv[ni] = bias[ocol + ni * 16];
#pragma unroll
    for (int mi = 0; mi < 4; ++mi)
#pragma unroll
      for (int r = 0; r < 4; ++r) {
        size_t rowoff = (size_t)(orow + mi * 16 + r) * N;
#pragma unroll
        for (int ni = 0; ni < 4; ++ni)
          C[rowoff + ocol + ni * 16] = acc[mi][ni][r] + bv[ni];
      }
  }
}

extern "C" void kernel_launch(void* const* d_in, const int* in_sizes, int n_in,
                              void* d_out, int out_size, void* d_ws, size_t ws_size,
                              hipStream_t stream) {
  const float* x    = (const float*)d_in[0];  // [B*T, OUT_H]
  const float* U    = (const float*)d_in[1];  // [IN_H, RANK]
  const float* S    = (const float*)d_in[2];  // [RANK]
  const float* V    = (const float*)d_in[3];  // [OUT_H, RANK]
  const float* bias = (const float*)d_in[4];  // [IN_H]

  const int RANK = in_sizes[2];               // 1024
  const int INH  = in_sizes[4];               // 4096
  const int OUTH = in_sizes[3] / RANK;        // 4096
  const int M    = in_sizes[0] / OUTH;        // 8192

  // workspace carve (bf16): Xb[M,OUTH] | Vt[RANK,OUTH] | Ub[INH,RANK] | Yb[M,RANK]
  unsigned short* Xb = (unsigned short*)d_ws;
  unsigned short* Vt = Xb + (size_t)M * OUTH;
  unsigned short* Ub = Vt + (size_t)RANK * OUTH;
  unsigned short* Yb = Ub + (size_t)INH * RANK;

  // prep
  cast_x_kernel<<<(int)(((size_t)M * OUTH) / 2048), 256, 0, stream>>>(x, Xb);
  transpose_v_kernel<<<dim3(RANK / 32, OUTH / 32), 256, 0, stream>>>(V, Vt, OUTH, RANK);
  prep_u_kernel<<<(int)(((size_t)INH * RANK) / 1024), 256, 0, stream>>>(U, S, Ub,
                                                                        (unsigned)(RANK - 1));
  // GEMM1: Yb[M,RANK] = Xb[M,OUTH] @ Vt[RANK,OUTH]^T   (bf16 out)
  gemm_bt_kernel<true><<<dim3(RANK / 128, M / 128), 256, 0, stream>>>(
      Xb, Vt, (void*)Yb, nullptr, M, RANK, OUTH);
  // GEMM2: out[M,INH] = Yb[M,RANK] @ Ub[INH,RANK]^T + bias   (fp32 out)
  gemm_bt_kernel<false><<<dim3(INH / 128, M / 128), 256, 0, stream>>>(
      Yb, Ub, d_out, bias, M, INH, RANK);
}

// Round 2
// 427.078 us; speedup vs baseline: 1.0077x; 1.0077x over previous
//
#include <hip/hip_runtime.h>
#include <stdint.h>

typedef __attribute__((ext_vector_type(4))) float  floatx4;
typedef __attribute__((ext_vector_type(8))) short  short8;
typedef __attribute__((ext_vector_type(8))) __bf16 bf16x8;

__device__ __forceinline__ unsigned short f2bf(float f) {
  unsigned int u = __builtin_bit_cast(unsigned int, f);
  u += 0x7fffu + ((u >> 16) & 1u);   // round-to-nearest-even
  return (unsigned short)(u >> 16);
}

// ---------------- cast x (fp32 -> bf16), 8 elems/thread ----------------
__global__ __launch_bounds__(256) void cast_x_kernel(const float* __restrict__ X,
                                                     unsigned short* __restrict__ Xb) {
  size_t i = ((size_t)blockIdx.x * 256 + threadIdx.x) * 8;
  const floatx4* p = (const floatx4*)(X + i);
  floatx4 a = p[0], b = p[1];
  union { unsigned short us[8]; short8 v; } o;
  o.us[0] = f2bf(a[0]); o.us[1] = f2bf(a[1]); o.us[2] = f2bf(a[2]); o.us[3] = f2bf(a[3]);
  o.us[4] = f2bf(b[0]); o.us[5] = f2bf(b[1]); o.us[6] = f2bf(b[2]); o.us[7] = f2bf(b[3]);
  *(short8*)(Xb + i) = o.v;
}

// ------------- transpose+cast V [rows,cols] -> Vt [cols,rows] bf16 -------------
__global__ __launch_bounds__(256) void transpose_v_kernel(const float* __restrict__ V,
                                                          unsigned short* __restrict__ Vt,
                                                          int rows, int cols) {
  __shared__ float tile[32][33];
  int bx = blockIdx.x * 32;
  int by = blockIdx.y * 32;
  int tx = threadIdx.x & 31;
  int ty = threadIdx.x >> 5;
  for (int i = ty; i < 32; i += 8)
    tile[i][tx] = V[(size_t)(by + i) * cols + bx + tx];
  __syncthreads();
  for (int i = ty; i < 32; i += 8)
    Vt[(size_t)(bx + i) * rows + by + tx] = f2bf(tile[tx][i]);
}

// ------------- U' = bf16(U * S broadcast), 4 elems/thread -------------
__global__ __launch_bounds__(256) void prep_u_kernel(const float* __restrict__ U,
                                                     const float* __restrict__ S,
                                                     unsigned short* __restrict__ Ub,
                                                     unsigned int rankMask) {
  size_t i = ((size_t)blockIdx.x * 256 + threadIdx.x) * 4;
  floatx4 u = *(const floatx4*)(U + i);
  floatx4 s = *(const floatx4*)(S + (i & (size_t)rankMask));
  union { unsigned short us[4]; unsigned long long v; } o;
  o.us[0] = f2bf(u[0] * s[0]); o.us[1] = f2bf(u[1] * s[1]);
  o.us[2] = f2bf(u[2] * s[2]); o.us[3] = f2bf(u[3] * s[3]);
  *(unsigned long long*)(Ub + i) = o.v;
}

// ---------------- m97-style gemm_bt: C[rows,N] = A[rows,K] * Bt[N,K]^T ----------------
// BM=128, BN = WN_TILES*32, BK=32. 256 threads = 4 waves in 2x2.
// 1D grid, banded swizzle: 8 row-panels per band x all GX col panels
// (keeps per-band working set = A-band + full B inside L2/LLC).
template <int WN_TILES, int GXSHIFT, bool STORE_BF16>
__global__ __launch_bounds__(256, 2)
void gemm_bt_kernel(const unsigned short* __restrict__ A,
                    const unsigned short* __restrict__ Bt,
                    void* __restrict__ Cv,
                    const float* __restrict__ bias,
                    int N, int K) {
  constexpr int BN = WN_TILES * 32;
  __shared__ unsigned short sA[128 * 32];
  __shared__ unsigned short sB[BN * 32];

  // --- banded swizzle (gridDim.y multiple of 8 guaranteed by launch) ---
  unsigned bid  = blockIdx.x;
  unsigned band = bid >> (3 + GXSHIFT);
  unsigned rem  = bid & ((8u << GXSHIFT) - 1u);
  unsigned by   = (band << 3) | (rem & 7u);   // row panel
  unsigned bx   = rem >> 3;                   // col panel

  const int tid  = threadIdx.x;
  const int lane = tid & 63;
  const int wave = tid >> 6;
  const int wm = (wave >> 1) * 64;                 // wave row offset
  const int wn = (wave & 1) * (WN_TILES * 16);     // wave col offset
  const int row0 = by * 128;
  const int col0 = bx * BN;

  floatx4 acc[4][WN_TILES];
  for (int i = 0; i < 4; ++i)
    for (int j = 0; j < WN_TILES; ++j)
      acc[i][j] = (floatx4){0.f, 0.f, 0.f, 0.f};

  const unsigned short* Ablk = A + (size_t)row0 * K;
  const unsigned short* Bblk = Bt + (size_t)col0 * K;

  // staging: 16B slots; A has 512 (2/thread), B has BN*4 (1 or 2/thread)
  const int r0 = tid >> 2,         c0 = (tid & 3) * 8;
  const int r1 = (256 + tid) >> 2, c1 = (tid & 3) * 8;
  const int base0 = (wave * 64) * 8;         // ushort idx, wave-uniform
  const int base1 = (256 + wave * 64) * 8;

  const int mrow = lane & 15;
  const int quad = lane >> 4;

  typedef const __attribute__((address_space(1))) void* gptr_t;
  typedef __attribute__((address_space(3))) void*       lptr_t;

  for (int k0 = 0; k0 < K; k0 += 32) {
    __builtin_amdgcn_global_load_lds((gptr_t)(Ablk + (size_t)r0 * K + k0 + c0),
                                     (lptr_t)(sA + base0), 16, 0, 0);
    __builtin_amdgcn_global_load_lds((gptr_t)(Ablk + (size_t)r1 * K + k0 + c1),
                                     (lptr_t)(sA + base1), 16, 0, 0);
    __builtin_amdgcn_global_load_lds((gptr_t)(Bblk + (size_t)r0 * K + k0 + c0),
                                     (lptr_t)(sB + base0), 16, 0, 0);
    if constexpr (BN == 128)
      __builtin_amdgcn_global_load_lds((gptr_t)(Bblk + (size_t)r1 * K + k0 + c1),
                                       (lptr_t)(sB + base1), 16, 0, 0);
    __syncthreads();

    bf16x8 af[4], bfr[WN_TILES];
#pragma unroll
    for (int mi = 0; mi < 4; ++mi)
      af[mi] = __builtin_bit_cast(bf16x8,
                *(const short8*)(sA + (wm + mi * 16 + mrow) * 32 + quad * 8));
#pragma unroll
    for (int ni = 0; ni < WN_TILES; ++ni)
      bfr[ni] = __builtin_bit_cast(bf16x8,
                *(const short8*)(sB + (wn + ni * 16 + mrow) * 32 + quad * 8));
#pragma unroll
    for (int mi = 0; mi < 4; ++mi)
#pragma unroll
      for (int ni = 0; ni < WN_TILES; ++ni)
        acc[mi][ni] = __builtin_amdgcn_mfma_f32_16x16x32_bf16(af[mi], bfr[ni],
                                                              acc[mi][ni], 0, 0, 0);
    __syncthreads();
  }

  // epilogue: C/D layout col=lane&15, row=quad*4+reg (verified m89/m91)
  const int orow = row0 + wm + quad * 4;
  const int ocol = col0 + wn + mrow;
  if (STORE_BF16) {
    unsigned short* C = (unsigned short*)Cv;
#pragma unroll
    for (int mi = 0; mi < 4; ++mi)
#pragma unroll
      for (int r = 0; r < 4; ++r) {
        size_t rowoff = (size_t)(orow + mi * 16 + r) * N;
#pragma unroll
        for (int ni = 0; ni < WN_TILES; ++ni)
          C[rowoff + ocol + ni * 16] = f2bf(acc[mi][ni][r]);
      }
  } else {
    float* C = (float*)Cv;
    float bv[WN_TILES];
#pragma unroll
    for (int ni = 0; ni < WN_TILES; ++ni) bv[ni] = bias[ocol + ni * 16];
#pragma unroll
    for (int mi = 0; mi < 4; ++mi)
#pragma unroll
      for (int r = 0; r < 4; ++r) {
        size_t rowoff = (size_t)(orow + mi * 16 + r) * N;
#pragma unroll
        for (int ni = 0; ni < WN_TILES; ++ni)
          C[rowoff + ocol + ni * 16] = acc[mi][ni][r] + bv[ni];
      }
  }
}

extern "C" void kernel_launch(void* const* d_in, const int* in_sizes, int n_in,
                              void* d_out, int out_size, void* d_ws, size_t ws_size,
                              hipStream_t stream) {
  const float* x    = (const float*)d_in[0];  // [B*T, OUT_H]
  const float* U    = (const float*)d_in[1];  // [IN_H, RANK]
  const float* S    = (const float*)d_in[2];  // [RANK]
  const float* V    = (const float*)d_in[3];  // [OUT_H, RANK]
  const float* bias = (const float*)d_in[4];  // [IN_H]

  const int RANK = in_sizes[2];               // 1024
  const int INH  = in_sizes[4];               // 4096
  const int OUTH = in_sizes[3] / RANK;        // 4096
  const int M    = in_sizes[0] / OUTH;        // 8192

  // workspace carve (bf16): Xb[M,OUTH] | Vt[RANK,OUTH] | Ub[INH,RANK] | Yb[M,RANK]
  unsigned short* Xb = (unsigned short*)d_ws;
  unsigned short* Vt = Xb + (size_t)M * OUTH;
  unsigned short* Ub = Vt + (size_t)RANK * OUTH;
  unsigned short* Yb = Ub + (size_t)INH * RANK;

  cast_x_kernel<<<(int)(((size_t)M * OUTH) / 2048), 256, 0, stream>>>(x, Xb);
  transpose_v_kernel<<<dim3(RANK / 32, OUTH / 32), 256, 0, stream>>>(V, Vt, OUTH, RANK);
  prep_u_kernel<<<(int)(((size_t)INH * RANK) / 1024), 256, 0, stream>>>(U, S, Ub,
                                                                        (unsigned)(RANK - 1));

  // GEMM1: Yb[M,RANK] = Xb @ Vt^T.  BN=64 -> GX = RANK/64 = 16 (GXSHIFT=4),
  // grid = 16 * (M/128=64) = 1024 blocks (4 blocks/CU).
  gemm_bt_kernel<2, 4, true><<<(RANK / 64) * (M / 128), 256, 0, stream>>>(
      Xb, Vt, (void*)Yb, nullptr, RANK, OUTH);

  // GEMM2: out[M,INH] = Yb @ Ub^T + bias.  BN=128 -> GX = INH/128 = 32 (GXSHIFT=5),
  // grid = 32 * 64 = 2048 blocks.
  gemm_bt_kernel<4, 5, false><<<(INH / 128) * (M / 128), 256, 0, stream>>>(
      Yb, Ub, d_out, bias, INH, RANK);
}

// Round 3
// 402.377 us; speedup vs baseline: 1.0695x; 1.0614x over previous
//
#include <hip/hip_runtime.h>
#include <stdint.h>

typedef __attribute__((ext_vector_type(4))) float  floatx4;
typedef __attribute__((ext_vector_type(8))) short  short8;
typedef __attribute__((ext_vector_type(8))) __bf16 bf16x8;

__device__ __forceinline__ unsigned short f2bf(float f) {
  unsigned int u = __builtin_bit_cast(unsigned int, f);
  u += 0x7fffu + ((u >> 16) & 1u);   // round-to-nearest-even
  return (unsigned short)(u >> 16);
}

typedef const __attribute__((address_space(1))) void* gptr_t;
typedef __attribute__((address_space(3))) void*       lptr_t;

// ---------------- fused prep: cast_x | transpose_v | prep_u ----------------
__global__ __launch_bounds__(256) void prep_fused(
    const float* __restrict__ X, const float* __restrict__ V,
    const float* __restrict__ U, const float* __restrict__ S,
    unsigned short* __restrict__ Xb, unsigned short* __restrict__ Vt,
    unsigned short* __restrict__ Ub,
    int castBlocks, int transTotal, int transGX, int vrows, int vcols,
    unsigned int rankMask) {
  __shared__ float tile[32][33];
  int bid = blockIdx.x;
  int tid = threadIdx.x;
  if (bid < castBlocks) {
    size_t i = ((size_t)bid * 256 + tid) * 8;
    const floatx4* p = (const floatx4*)(X + i);
    floatx4 a = p[0], b = p[1];
    union { unsigned short us[8]; short8 v; } o;
    o.us[0] = f2bf(a[0]); o.us[1] = f2bf(a[1]); o.us[2] = f2bf(a[2]); o.us[3] = f2bf(a[3]);
    o.us[4] = f2bf(b[0]); o.us[5] = f2bf(b[1]); o.us[6] = f2bf(b[2]); o.us[7] = f2bf(b[3]);
    *(short8*)(Xb + i) = o.v;
  } else if (bid < castBlocks + transTotal) {
    int b  = bid - castBlocks;
    int bx = (b % transGX) * 32;     // rank dim
    int by = (b / transGX) * 32;     // out_h dim
    int tx = tid & 31;
    int ty = tid >> 5;
    for (int i = ty; i < 32; i += 8)
      tile[i][tx] = V[(size_t)(by + i) * vcols + bx + tx];
    __syncthreads();
    for (int i = ty; i < 32; i += 8)
      Vt[(size_t)(bx + i) * vrows + by + tx] = f2bf(tile[tx][i]);
  } else {
    int b = bid - castBlocks - transTotal;
    size_t i = ((size_t)b * 256 + tid) * 4;
    floatx4 u = *(const floatx4*)(U + i);
    floatx4 s = *(const floatx4*)(S + (i & (size_t)rankMask));
    union { unsigned short us[4]; unsigned long long v; } o;
    o.us[0] = f2bf(u[0] * s[0]); o.us[1] = f2bf(u[1] * s[1]);
    o.us[2] = f2bf(u[2] * s[2]); o.us[3] = f2bf(u[3] * s[3]);
    *(unsigned long long*)(Ub + i) = o.v;
  }
}

// ---------------- GEMM1: Yb[M,N] bf16 = A[M,K] @ Bt[N,K]^T ----------------
// BM=128, BN=128, BK=64 (two 32-wide sub-tiles, one barrier pair per 64-K).
// 4 waves 2x2, wave-tile 64x64 (4x4 of 16x16x32 MFMA). Banded swizzle.
__global__ __launch_bounds__(256, 2)
void gemm1_kernel(const unsigned short* __restrict__ A,
                  const unsigned short* __restrict__ Bt,
                  unsigned short* __restrict__ C,
                  int N, int K, int GX) {
  __shared__ unsigned short sA[2][128 * 32];
  __shared__ unsigned short sB[2][128 * 32];

  const int tid  = threadIdx.x;
  const int lane = tid & 63;
  const int wave = tid >> 6;
  const int wm = (wave >> 1) * 64;
  const int wn = (wave & 1) * 64;

  unsigned bid  = blockIdx.x;
  unsigned bw   = 8u * GX;
  unsigned band = bid / bw, rem = bid % bw;
  unsigned by   = band * 8 + (rem & 7u);
  unsigned bx   = rem >> 3;
  const int row0 = by * 128, col0 = bx * 128;

  floatx4 acc[4][4];
#pragma unroll
  for (int i = 0; i < 4; ++i)
#pragma unroll
    for (int j = 0; j < 4; ++j) acc[i][j] = (floatx4){0.f, 0.f, 0.f, 0.f};

  const unsigned short* Ablk = A + (size_t)row0 * K;
  const unsigned short* Bblk = Bt + (size_t)col0 * K;

  const int r0 = tid >> 2, c0 = (tid & 3) * 8;   // j=0 slot; j=1 -> r0+64
  const int ldso0 = (wave * 64) * 8;             // ushort idx within sub-tile
  const int ldso1 = (256 + wave * 64) * 8;
  const int mrow = lane & 15, quad = lane >> 4;

  for (int k0 = 0; k0 < K; k0 += 64) {
#pragma unroll
    for (int t = 0; t < 2; ++t) {
      const int kk = k0 + t * 32;
      __builtin_amdgcn_global_load_lds((gptr_t)(Ablk + (size_t)r0 * K + kk + c0),
                                       (lptr_t)(sA[t] + ldso0), 16, 0, 0);
      __builtin_amdgcn_global_load_lds((gptr_t)(Ablk + (size_t)(r0 + 64) * K + kk + c0),
                                       (lptr_t)(sA[t] + ldso1), 16, 0, 0);
      __builtin_amdgcn_global_load_lds((gptr_t)(Bblk + (size_t)r0 * K + kk + c0),
                                       (lptr_t)(sB[t] + ldso0), 16, 0, 0);
      __builtin_amdgcn_global_load_lds((gptr_t)(Bblk + (size_t)(r0 + 64) * K + kk + c0),
                                       (lptr_t)(sB[t] + ldso1), 16, 0, 0);
    }
    __syncthreads();
#pragma unroll
    for (int t = 0; t < 2; ++t) {
      bf16x8 af[4], bfr[4];
#pragma unroll
      for (int mi = 0; mi < 4; ++mi)
        af[mi] = __builtin_bit_cast(bf16x8,
                  *(const short8*)(sA[t] + (wm + mi * 16 + mrow) * 32 + quad * 8));
#pragma unroll
      for (int ni = 0; ni < 4; ++ni)
        bfr[ni] = __builtin_bit_cast(bf16x8,
                  *(const short8*)(sB[t] + (wn + ni * 16 + mrow) * 32 + quad * 8));
#pragma unroll
      for (int mi = 0; mi < 4; ++mi)
#pragma unroll
        for (int ni = 0; ni < 4; ++ni)
          acc[mi][ni] = __builtin_amdgcn_mfma_f32_16x16x32_bf16(af[mi], bfr[ni],
                                                                acc[mi][ni], 0, 0, 0);
    }
    __syncthreads();
  }

  const int orow = row0 + wm + quad * 4;
  const int ocol = col0 + wn + mrow;
#pragma unroll
  for (int mi = 0; mi < 4; ++mi)
#pragma unroll
    for (int r = 0; r < 4; ++r) {
      size_t rowoff = (size_t)(orow + mi * 16 + r) * N;
#pragma unroll
      for (int ni = 0; ni < 4; ++ni)
        C[rowoff + ocol + ni * 16] = f2bf(acc[mi][ni][r]);
    }
}

// ---------------- GEMM2: C[M,N] fp32 = A[M,K] @ Bt[N,K]^T + bias ----------------
// BM=256, BN=128, BK=32. 4 waves 2x2, wave-tile 128x64 (8x4 of 16x16x32).
__global__ __launch_bounds__(256, 2)
void gemm2_kernel(const unsigned short* __restrict__ A,
                  const unsigned short* __restrict__ Bt,
                  float* __restrict__ C, const float* __restrict__ bias,
                  int N, int K, int GX) {
  __shared__ unsigned short sA[256 * 32];
  __shared__ unsigned short sB[128 * 32];

  const int tid  = threadIdx.x;
  const int lane = tid & 63;
  const int wave = tid >> 6;
  const int wm = (wave >> 1) * 128;
  const int wn = (wave & 1) * 64;

  unsigned bid  = blockIdx.x;
  unsigned bw   = 8u * GX;
  unsigned band = bid / bw, rem = bid % bw;
  unsigned by   = band * 8 + (rem & 7u);
  unsigned bx   = rem >> 3;
  const int row0 = by * 256, col0 = bx * 128;

  floatx4 acc[8][4];
#pragma unroll
  for (int i = 0; i < 8; ++i)
#pragma unroll
    for (int j = 0; j < 4; ++j) acc[i][j] = (floatx4){0.f, 0.f, 0.f, 0.f};

  const unsigned short* Ablk = A + (size_t)row0 * K;
  const unsigned short* Bblk = Bt + (size_t)col0 * K;

  const int r0 = tid >> 2, c0 = (tid & 3) * 8;
  const int mrow = lane & 15, quad = lane >> 4;

  for (int k0 = 0; k0 < K; k0 += 32) {
#pragma unroll
    for (int j = 0; j < 4; ++j)   // A: 256 rows = 1024 slots
      __builtin_amdgcn_global_load_lds((gptr_t)(Ablk + (size_t)(r0 + j * 64) * K + k0 + c0),
                                       (lptr_t)(sA + (j * 256 + wave * 64) * 8), 16, 0, 0);
#pragma unroll
    for (int j = 0; j < 2; ++j)   // B: 128 rows = 512 slots
      __builtin_amdgcn_global_load_lds((gptr_t)(Bblk + (size_t)(r0 + j * 64) * K + k0 + c0),
                                       (lptr_t)(sB + (j * 256 + wave * 64) * 8), 16, 0, 0);
    __syncthreads();

    bf16x8 af[8], bfr[4];
#pragma unroll
    for (int mi = 0; mi < 8; ++mi)
      af[mi] = __builtin_bit_cast(bf16x8,
                *(const short8*)(sA + (wm + mi * 16 + mrow) * 32 + quad * 8));
#pragma unroll
    for (int ni = 0; ni < 4; ++ni)
      bfr[ni] = __builtin_bit_cast(bf16x8,
                *(const short8*)(sB + (wn + ni * 16 + mrow) * 32 + quad * 8));
#pragma unroll
    for (int mi = 0; mi < 8; ++mi)
#pragma unroll
      for (int ni = 0; ni < 4; ++ni)
        acc[mi][ni] = __builtin_amdgcn_mfma_f32_16x16x32_bf16(af[mi], bfr[ni],
                                                              acc[mi][ni], 0, 0, 0);
    __syncthreads();
  }

  const int orow = row0 + wm + quad * 4;
  const int ocol = col0 + wn + mrow;
  float bv[4];
#pragma unroll
  for (int ni = 0; ni < 4; ++ni) bv[ni] = bias[ocol + ni * 16];
#pragma unroll
  for (int mi = 0; mi < 8; ++mi)
#pragma unroll
    for (int r = 0; r < 4; ++r) {
      size_t rowoff = (size_t)(orow + mi * 16 + r) * N;
#pragma unroll
      for (int ni = 0; ni < 4; ++ni)
        C[rowoff + ocol + ni * 16] = acc[mi][ni][r] + bv[ni];
    }
}

extern "C" void kernel_launch(void* const* d_in, const int* in_sizes, int n_in,
                              void* d_out, int out_size, void* d_ws, size_t ws_size,
                              hipStream_t stream) {
  const float* x    = (const float*)d_in[0];  // [B*T, OUT_H]
  const float* U    = (const float*)d_in[1];  // [IN_H, RANK]
  const float* S    = (const float*)d_in[2];  // [RANK]
  const float* V    = (const float*)d_in[3];  // [OUT_H, RANK]
  const float* bias = (const float*)d_in[4];  // [IN_H]

  const int RANK = in_sizes[2];               // 1024
  const int INH  = in_sizes[4];               // 4096
  const int OUTH = in_sizes[3] / RANK;        // 4096
  const int M    = in_sizes[0] / OUTH;        // 8192

  unsigned short* Xb = (unsigned short*)d_ws;
  unsigned short* Vt = Xb + (size_t)M * OUTH;
  unsigned short* Ub = Vt + (size_t)RANK * OUTH;
  unsigned short* Yb = Ub + (size_t)INH * RANK;

  const int castBlocks = (int)(((size_t)M * OUTH) / 2048);
  const int transGX    = RANK / 32;
  const int transTotal = transGX * (OUTH / 32);
  const int prepUBlk   = (int)(((size_t)INH * RANK) / 1024);
  prep_fused<<<castBlocks + transTotal + prepUBlk, 256, 0, stream>>>(
      x, V, U, S, Xb, Vt, Ub, castBlocks, transTotal, transGX, OUTH, RANK,
      (unsigned)(RANK - 1));

  // GEMM1: grid = (M/128)*(RANK/128) = 64*8 = 512, GX=8
  gemm1_kernel<<<(M / 128) * (RANK / 128), 256, 0, stream>>>(
      Xb, Vt, Yb, RANK, OUTH, RANK / 128);

  // GEMM2: grid = (M/256)*(INH/128) = 32*32 = 1024, GX=32
  gemm2_kernel<<<(M / 256) * (INH / 128), 256, 0, stream>>>(
      Yb, Ub, (float*)d_out, bias, INH, RANK, INH / 128);
}